// Round 1
// baseline (4111.612 us; speedup 1.0000x reference)
//
#include <hip/hip_runtime.h>

#define NATOMS 262144
#define NPAIRS 8388608

// Morse constants
#define C_SIGMA   1.0f
#define C_EPS     5.0f
#define C_ALPHA   5.0f
#define C_CUTOFF  2.5f

// d_out layout (float32, flat, return order):
// [0]                  energy (scalar)
// [1 .. 1+N)           atom_energies
// [1+N .. 1+4N)        forces (N,3) row-major
// [1+4N .. 1+4N+9)     stress (3,3) row-major
#define OUT_E       0
#define OUT_AE      1
#define OUT_F       (1 + NATOMS)
#define OUT_S       (1 + 4 * NATOMS)

__global__ __launch_bounds__(256) void zero_out_kernel(float* __restrict__ out, int n) {
    int idx = blockIdx.x * blockDim.x + threadIdx.x;
    if (idx < n) out[idx] = 0.0f;
}

__global__ __launch_bounds__(256) void morse_pairs_kernel(
    const float* __restrict__ pos,     // [NATOMS,3]
    const float* __restrict__ cell,    // [3,3]
    const float* __restrict__ shifts,  // [NPAIRS,3]
    const int*   __restrict__ mi,      // [NPAIRS]
    const int*   __restrict__ mj,      // [NPAIRS]
    float* __restrict__ out)
{
    float* __restrict__ atom_e = out + OUT_AE;
    float* __restrict__ forces = out + OUT_F;
    float* __restrict__ stress = out + OUT_S;

    // cell is tiny & uniform: scalar loads, L2/L1-cached
    const float c00 = cell[0], c01 = cell[1], c02 = cell[2];
    const float c10 = cell[3], c11 = cell[4], c12 = cell[5];
    const float c20 = cell[6], c21 = cell[7], c22 = cell[8];
    const float det = c00 * (c11 * c22 - c12 * c21)
                    - c01 * (c10 * c22 - c12 * c20)
                    + c02 * (c10 * c21 - c11 * c20);
    const float inv_vol = 1.0f / fabsf(det);

    const int tid  = blockIdx.x * blockDim.x + threadIdx.x;
    const int base = tid * 4;   // 4 pairs per thread, grid sized so base+3 < NPAIRS

    // coalesced vector loads: 16B mapping rows, 48B shifts per thread
    const int4 i4 = *reinterpret_cast<const int4*>(mi + base);
    const int4 j4 = *reinterpret_cast<const int4*>(mj + base);
    const float4* shp = reinterpret_cast<const float4*>(shifts + (size_t)base * 3);
    const float4 s_a = shp[0];
    const float4 s_b = shp[1];
    const float4 s_c = shp[2];

    const int   idx_i[4] = { i4.x, i4.y, i4.z, i4.w };
    const int   idx_j[4] = { j4.x, j4.y, j4.z, j4.w };
    const float sh[12]   = { s_a.x, s_a.y, s_a.z, s_a.w,
                             s_b.x, s_b.y, s_b.z, s_b.w,
                             s_c.x, s_c.y, s_c.z, s_c.w };

    float e_acc = 0.0f;
    float sxx = 0.0f, syy = 0.0f, szz = 0.0f;
    float sxy = 0.0f, sxz = 0.0f, syz = 0.0f;

#pragma unroll
    for (int k = 0; k < 4; ++k) {
        const int i = idx_i[k];
        const int j = idx_j[k];
        const float sx = sh[3 * k + 0];
        const float sy = sh[3 * k + 1];
        const float sz = sh[3 * k + 2];

        const float pix = pos[3 * i + 0], piy = pos[3 * i + 1], piz = pos[3 * i + 2];
        const float pjx = pos[3 * j + 0], pjy = pos[3 * j + 1], pjz = pos[3 * j + 2];

        const float dx = pjx - pix + sx * c00 + sy * c10 + sz * c20;
        const float dy = pjy - piy + sx * c01 + sy * c11 + sz * c21;
        const float dz = pjz - piz + sx * c02 + sy * c12 + sz * c22;

        const float r2 = dx * dx + dy * dy + dz * dz;
        const float r  = sqrtf(r2);

        // masked-out pairs contribute exactly 0.0 -> skip atomics entirely
        if (r < C_CUTOFF && r > 1e-10f) {
            const float ex = __expf(-C_ALPHA * (r - C_SIGMA));
            const float om = 1.0f - ex;
            const float pe = C_EPS * om * om - C_EPS;
            const float pf = -2.0f * C_ALPHA * C_EPS * ex * om;  // -dE/dr
            const float t  = pf / r;                              // scale for dr

            const float fx = t * dx, fy = t * dy, fz = t * dz;

            e_acc += pe;
            sxx += t * dx * dx;  syy += t * dy * dy;  szz += t * dz * dz;
            sxy += t * dx * dy;  sxz += t * dx * dz;  syz += t * dy * dz;

            const float he = 0.5f * pe;
            atomicAdd(atom_e + i, he);
            atomicAdd(atom_e + j, he);
            atomicAdd(forces + 3 * i + 0, -fx);
            atomicAdd(forces + 3 * i + 1, -fy);
            atomicAdd(forces + 3 * i + 2, -fz);
            atomicAdd(forces + 3 * j + 0,  fx);
            atomicAdd(forces + 3 * j + 1,  fy);
            atomicAdd(forces + 3 * j + 2,  fz);
        }
    }

    // wave-level (64-lane) reduction of energy + 6 stress components
#pragma unroll
    for (int off = 32; off > 0; off >>= 1) {
        e_acc += __shfl_down(e_acc, off);
        sxx   += __shfl_down(sxx, off);
        syy   += __shfl_down(syy, off);
        szz   += __shfl_down(szz, off);
        sxy   += __shfl_down(sxy, off);
        sxz   += __shfl_down(sxz, off);
        syz   += __shfl_down(syz, off);
    }

    if ((threadIdx.x & 63) == 0) {
        atomicAdd(out + OUT_E, 0.5f * e_acc);
        const float s = -inv_vol;
        atomicAdd(stress + 0, s * sxx);
        atomicAdd(stress + 4, s * syy);
        atomicAdd(stress + 8, s * szz);
        atomicAdd(stress + 1, s * sxy);
        atomicAdd(stress + 3, s * sxy);
        atomicAdd(stress + 2, s * sxz);
        atomicAdd(stress + 6, s * sxz);
        atomicAdd(stress + 5, s * syz);
        atomicAdd(stress + 7, s * syz);
    }
}

extern "C" void kernel_launch(void* const* d_in, const int* in_sizes, int n_in,
                              void* d_out, int out_size, void* d_ws, size_t ws_size,
                              hipStream_t stream) {
    const float* pos    = (const float*)d_in[0];
    const float* cell   = (const float*)d_in[1];
    const float* shifts = (const float*)d_in[2];
    const int*   map    = (const int*)d_in[3];   // [2, NPAIRS]
    float* out = (float*)d_out;

    // zero outputs (harness poisons d_out with 0xAA before every timed launch)
    {
        const int n = out_size;
        const int blocks = (n + 255) / 256;
        zero_out_kernel<<<blocks, 256, 0, stream>>>(out, n);
    }

    // 4 pairs/thread, 256 threads/block -> 1024 pairs/block; NPAIRS/1024 = 8192 blocks
    morse_pairs_kernel<<<NPAIRS / 1024, 256, 0, stream>>>(
        pos, cell, shifts, map, map + NPAIRS, out);
}

// Round 2
// 1130.999 us; speedup vs baseline: 3.6354x; 3.6354x over previous
//
#include <hip/hip_runtime.h>

#define NATOMS 262144
#define NPAIRS 8388608

// Morse constants
#define C_SIGMA   1.0f
#define C_EPS     5.0f
#define C_ALPHA   5.0f
#define C_CUTOFF  2.5f

// d_out layout (float32, flat, return order):
// [0] energy | [1..1+N) atom_e | [1+N..1+4N) forces | [1+4N..+9) stress
#define OUT_E 0
#define OUT_AE 1
#define OUT_F (1 + NATOMS)
#define OUT_S (1 + 4 * NATOMS)

// ws layout: NC copies, each STRIDE floats:
//   [4*a + 0..3] = (0.5*pe, fx, fy, fz) accumulators per atom a
//   tail at 4*NATOMS: [energy, sxx, syy, szz, sxy, sxz, syz] (+pad)
#define WS_STRIDE ((size_t)(4 * NATOMS + 16))
#define WS_TAIL (4 * NATOMS)

typedef int   i32x4 __attribute__((ext_vector_type(4)));
typedef float f32x4 __attribute__((ext_vector_type(4)));

__device__ __forceinline__ int xcc_id() {
    // s_getreg_b32 hwreg(HW_REG_XCC_ID=20, offset 0, size 4)
    return (int)(__builtin_amdgcn_s_getreg((3 << 11) | 20) & 7);
}

// Non-scoped (XCD-L2) float atomic add: executes in the local TCC, never
// leaves the XCD. Only correct because each ws copy is touched by exactly
// one XCD (indexed by the hardware XCC_ID).
__device__ __forceinline__ void atomic_add_l2(float* p, float v) {
    asm volatile("global_atomic_add_f32 %0, %1, off" :: "v"(p), "v"(v) : "memory");
}
__device__ __forceinline__ void atomic_add4_l2(float* p, float a0, float a1, float a2, float a3) {
    asm volatile(
        "global_atomic_add_f32 %0, %1, off\n\t"
        "global_atomic_add_f32 %0, %2, off offset:4\n\t"
        "global_atomic_add_f32 %0, %3, off offset:8\n\t"
        "global_atomic_add_f32 %0, %4, off offset:12"
        :: "v"(p), "v"(a0), "v"(a1), "v"(a2), "v"(a3) : "memory");
}

__global__ __launch_bounds__(256) void zero_f32x4_kernel(float* __restrict__ p, size_t n4) {
    size_t idx = (size_t)blockIdx.x * blockDim.x + threadIdx.x;
    const size_t step = (size_t)gridDim.x * blockDim.x;
    f32x4 z = {0.0f, 0.0f, 0.0f, 0.0f};
    for (; idx < n4; idx += step)
        __builtin_nontemporal_store(z, reinterpret_cast<f32x4*>(p) + idx);
}

__global__ __launch_bounds__(256) void zero_out_kernel(float* __restrict__ out, int n) {
    int idx = blockIdx.x * blockDim.x + threadIdx.x;
    if (idx < n) out[idx] = 0.0f;
}

// ---------------- main pair kernel (privatized-ws variant) ----------------
template <bool USE_XCC>
__global__ __launch_bounds__(256) void morse_pairs_ws(
    const float* __restrict__ pos, const float* __restrict__ cell,
    const float* __restrict__ shifts, const int* __restrict__ mi,
    const int* __restrict__ mj, float* __restrict__ ws)
{
    float* __restrict__ copy = ws + (USE_XCC ? (size_t)xcc_id() * WS_STRIDE : 0);

    const float c00 = cell[0], c01 = cell[1], c02 = cell[2];
    const float c10 = cell[3], c11 = cell[4], c12 = cell[5];
    const float c20 = cell[6], c21 = cell[7], c22 = cell[8];
    const float det = c00 * (c11 * c22 - c12 * c21)
                    - c01 * (c10 * c22 - c12 * c20)
                    + c02 * (c10 * c21 - c11 * c20);
    const float inv_vol = 1.0f / fabsf(det);

    const int tid  = blockIdx.x * blockDim.x + threadIdx.x;
    const int base = tid * 4;

    // streaming inputs: non-temporal so they don't evict the L2 atomic set
    const i32x4 i4 = __builtin_nontemporal_load(reinterpret_cast<const i32x4*>(mi + base));
    const i32x4 j4 = __builtin_nontemporal_load(reinterpret_cast<const i32x4*>(mj + base));
    const f32x4* shp = reinterpret_cast<const f32x4*>(shifts + (size_t)base * 3);
    const f32x4 s_a = __builtin_nontemporal_load(shp + 0);
    const f32x4 s_b = __builtin_nontemporal_load(shp + 1);
    const f32x4 s_c = __builtin_nontemporal_load(shp + 2);

    const int   idx_i[4] = { i4.x, i4.y, i4.z, i4.w };
    const int   idx_j[4] = { j4.x, j4.y, j4.z, j4.w };
    const float sh[12]   = { s_a.x, s_a.y, s_a.z, s_a.w,
                             s_b.x, s_b.y, s_b.z, s_b.w,
                             s_c.x, s_c.y, s_c.z, s_c.w };

    float e_acc = 0.0f;
    float sxx = 0.0f, syy = 0.0f, szz = 0.0f;
    float sxy = 0.0f, sxz = 0.0f, syz = 0.0f;

#pragma unroll
    for (int k = 0; k < 4; ++k) {
        const int i = idx_i[k];
        const int j = idx_j[k];
        const float sx = sh[3 * k + 0];
        const float sy = sh[3 * k + 1];
        const float sz = sh[3 * k + 2];

        const float pix = pos[3 * i + 0], piy = pos[3 * i + 1], piz = pos[3 * i + 2];
        const float pjx = pos[3 * j + 0], pjy = pos[3 * j + 1], pjz = pos[3 * j + 2];

        const float dx = pjx - pix + sx * c00 + sy * c10 + sz * c20;
        const float dy = pjy - piy + sx * c01 + sy * c11 + sz * c21;
        const float dz = pjz - piz + sx * c02 + sy * c12 + sz * c22;

        const float r2 = dx * dx + dy * dy + dz * dz;
        const float r  = sqrtf(r2);

        if (r < C_CUTOFF && r > 1e-10f) {
            const float ex = __expf(-C_ALPHA * (r - C_SIGMA));
            const float om = 1.0f - ex;
            const float pe = C_EPS * om * om - C_EPS;
            const float pf = -2.0f * C_ALPHA * C_EPS * ex * om;  // -dE/dr
            const float t  = pf / r;

            const float fx = t * dx, fy = t * dy, fz = t * dz;

            e_acc += pe;
            sxx += t * dx * dx;  syy += t * dy * dy;  szz += t * dz * dz;
            sxy += t * dx * dy;  sxz += t * dx * dz;  syz += t * dy * dz;

            const float he = 0.5f * pe;
            float* pi = copy + 4 * (size_t)i;
            float* pj = copy + 4 * (size_t)j;
            if constexpr (USE_XCC) {
                atomic_add4_l2(pi, he, -fx, -fy, -fz);
                atomic_add4_l2(pj, he,  fx,  fy,  fz);
            } else {
                atomicAdd(pi + 0, he);  atomicAdd(pi + 1, -fx);
                atomicAdd(pi + 2, -fy); atomicAdd(pi + 3, -fz);
                atomicAdd(pj + 0, he);  atomicAdd(pj + 1,  fx);
                atomicAdd(pj + 2,  fy); atomicAdd(pj + 3,  fz);
            }
        }
    }

    // wave reduce (64 lanes) of energy + 6 stress comps
#pragma unroll
    for (int off = 32; off > 0; off >>= 1) {
        e_acc += __shfl_down(e_acc, off);
        sxx   += __shfl_down(sxx, off);
        syy   += __shfl_down(syy, off);
        szz   += __shfl_down(szz, off);
        sxy   += __shfl_down(sxy, off);
        sxz   += __shfl_down(sxz, off);
        syz   += __shfl_down(syz, off);
    }

    // block reduce via LDS, single thread issues 7 tail atomics
    __shared__ float red[4][7];
    const int lane = threadIdx.x & 63;
    const int wid  = threadIdx.x >> 6;
    if (lane == 0) {
        red[wid][0] = e_acc;
        red[wid][1] = sxx; red[wid][2] = syy; red[wid][3] = szz;
        red[wid][4] = sxy; red[wid][5] = sxz; red[wid][6] = syz;
    }
    __syncthreads();
    if (threadIdx.x == 0) {
        float acc[7];
#pragma unroll
        for (int c = 0; c < 7; ++c)
            acc[c] = red[0][c] + red[1][c] + red[2][c] + red[3][c];
        const float s = -inv_vol;
        float* tail = copy + WS_TAIL;
        if constexpr (USE_XCC) {
            atomic_add_l2(tail + 0, 0.5f * acc[0]);
#pragma unroll
            for (int c = 1; c < 7; ++c) atomic_add_l2(tail + c, s * acc[c]);
        } else {
            atomicAdd(tail + 0, 0.5f * acc[0]);
#pragma unroll
            for (int c = 1; c < 7; ++c) atomicAdd(tail + c, s * acc[c]);
        }
    }
}

// ---------------- reduce ws copies -> d_out (writes every element) -------
__global__ __launch_bounds__(256) void reduce_ws_kernel(
    const float* __restrict__ ws, float* __restrict__ out, int ncopies)
{
    const int a = blockIdx.x * blockDim.x + threadIdx.x;
    if (a < NATOMS) {
        float ax = 0.0f, ay = 0.0f, az = 0.0f, aw = 0.0f;
        for (int c = 0; c < ncopies; ++c) {
            const f32x4 v = *reinterpret_cast<const f32x4*>(ws + (size_t)c * WS_STRIDE + 4 * (size_t)a);
            ax += v.x; ay += v.y; az += v.z; aw += v.w;
        }
        out[OUT_AE + a] = ax;
        float* f = out + OUT_F + 3 * (size_t)a;
        f[0] = ay; f[1] = az; f[2] = aw;
    }
    if (blockIdx.x == 0 && threadIdx.x < 7) {
        float s = 0.0f;
        for (int c = 0; c < ncopies; ++c)
            s += ws[(size_t)c * WS_STRIDE + WS_TAIL + threadIdx.x];
        float* stress = out + OUT_S;
        switch (threadIdx.x) {
            case 0: out[OUT_E] = s; break;
            case 1: stress[0] = s; break;
            case 2: stress[4] = s; break;
            case 3: stress[8] = s; break;
            case 4: stress[1] = s; stress[3] = s; break;
            case 5: stress[2] = s; stress[6] = s; break;
            case 6: stress[5] = s; stress[7] = s; break;
        }
    }
}

// ---------------- last-resort direct path (device atomics into d_out) ----
__global__ __launch_bounds__(256) void morse_pairs_direct(
    const float* __restrict__ pos, const float* __restrict__ cell,
    const float* __restrict__ shifts, const int* __restrict__ mi,
    const int* __restrict__ mj, float* __restrict__ out)
{
    float* atom_e = out + OUT_AE;
    float* forces = out + OUT_F;
    float* stress = out + OUT_S;

    const float c00 = cell[0], c01 = cell[1], c02 = cell[2];
    const float c10 = cell[3], c11 = cell[4], c12 = cell[5];
    const float c20 = cell[6], c21 = cell[7], c22 = cell[8];
    const float det = c00 * (c11 * c22 - c12 * c21)
                    - c01 * (c10 * c22 - c12 * c20)
                    + c02 * (c10 * c21 - c11 * c20);
    const float inv_vol = 1.0f / fabsf(det);

    const int tid  = blockIdx.x * blockDim.x + threadIdx.x;
    const int base = tid * 4;
    const i32x4 i4 = *reinterpret_cast<const i32x4*>(mi + base);
    const i32x4 j4 = *reinterpret_cast<const i32x4*>(mj + base);
    const f32x4* shp = reinterpret_cast<const f32x4*>(shifts + (size_t)base * 3);
    const f32x4 s_a = shp[0], s_b = shp[1], s_c = shp[2];
    const int   idx_i[4] = { i4.x, i4.y, i4.z, i4.w };
    const int   idx_j[4] = { j4.x, j4.y, j4.z, j4.w };
    const float sh[12]   = { s_a.x, s_a.y, s_a.z, s_a.w,
                             s_b.x, s_b.y, s_b.z, s_b.w,
                             s_c.x, s_c.y, s_c.z, s_c.w };

    float e_acc = 0.0f, sxx = 0, syy = 0, szz = 0, sxy = 0, sxz = 0, syz = 0;
#pragma unroll
    for (int k = 0; k < 4; ++k) {
        const int i = idx_i[k], j = idx_j[k];
        const float sx = sh[3*k], sy = sh[3*k+1], sz = sh[3*k+2];
        const float dx = pos[3*j]   - pos[3*i]   + sx*c00 + sy*c10 + sz*c20;
        const float dy = pos[3*j+1] - pos[3*i+1] + sx*c01 + sy*c11 + sz*c21;
        const float dz = pos[3*j+2] - pos[3*i+2] + sx*c02 + sy*c12 + sz*c22;
        const float r = sqrtf(dx*dx + dy*dy + dz*dz);
        if (r < C_CUTOFF && r > 1e-10f) {
            const float ex = __expf(-C_ALPHA * (r - C_SIGMA));
            const float om = 1.0f - ex;
            const float pe = C_EPS * om * om - C_EPS;
            const float t  = (-2.0f * C_ALPHA * C_EPS * ex * om) / r;
            const float fx = t*dx, fy = t*dy, fz = t*dz;
            e_acc += pe;
            sxx += t*dx*dx; syy += t*dy*dy; szz += t*dz*dz;
            sxy += t*dx*dy; sxz += t*dx*dz; syz += t*dy*dz;
            const float he = 0.5f * pe;
            atomicAdd(atom_e + i, he);           atomicAdd(atom_e + j, he);
            atomicAdd(forces + 3*i + 0, -fx);    atomicAdd(forces + 3*j + 0, fx);
            atomicAdd(forces + 3*i + 1, -fy);    atomicAdd(forces + 3*j + 1, fy);
            atomicAdd(forces + 3*i + 2, -fz);    atomicAdd(forces + 3*j + 2, fz);
        }
    }
#pragma unroll
    for (int off = 32; off > 0; off >>= 1) {
        e_acc += __shfl_down(e_acc, off);
        sxx += __shfl_down(sxx, off); syy += __shfl_down(syy, off);
        szz += __shfl_down(szz, off); sxy += __shfl_down(sxy, off);
        sxz += __shfl_down(sxz, off); syz += __shfl_down(syz, off);
    }
    if ((threadIdx.x & 63) == 0) {
        atomicAdd(out + OUT_E, 0.5f * e_acc);
        const float s = -inv_vol;
        atomicAdd(stress + 0, s*sxx); atomicAdd(stress + 4, s*syy);
        atomicAdd(stress + 8, s*szz);
        atomicAdd(stress + 1, s*sxy); atomicAdd(stress + 3, s*sxy);
        atomicAdd(stress + 2, s*sxz); atomicAdd(stress + 6, s*sxz);
        atomicAdd(stress + 5, s*syz); atomicAdd(stress + 7, s*syz);
    }
}

extern "C" void kernel_launch(void* const* d_in, const int* in_sizes, int n_in,
                              void* d_out, int out_size, void* d_ws, size_t ws_size,
                              hipStream_t stream) {
    const float* pos    = (const float*)d_in[0];
    const float* cell   = (const float*)d_in[1];
    const float* shifts = (const float*)d_in[2];
    const int*   map    = (const int*)d_in[3];   // [2, NPAIRS]
    float* out = (float*)d_out;
    float* ws  = (float*)d_ws;

    const size_t copy_bytes = WS_STRIDE * sizeof(float);

    if (ws_size >= 8 * copy_bytes) {
        // mode A: 8 XCD-private copies, L2-local atomics
        const size_t n4 = 8 * WS_STRIDE / 4;
        zero_f32x4_kernel<<<2048, 256, 0, stream>>>(ws, n4);
        morse_pairs_ws<true><<<NPAIRS / 1024, 256, 0, stream>>>(
            pos, cell, shifts, map, map + NPAIRS, ws);
        reduce_ws_kernel<<<NATOMS / 256, 256, 0, stream>>>(ws, out, 8);
    } else if (ws_size >= copy_bytes) {
        // mode B: single ws copy, device-scope atomics
        const size_t n4 = WS_STRIDE / 4;
        zero_f32x4_kernel<<<2048, 256, 0, stream>>>(ws, n4);
        morse_pairs_ws<false><<<NPAIRS / 1024, 256, 0, stream>>>(
            pos, cell, shifts, map, map + NPAIRS, ws);
        reduce_ws_kernel<<<NATOMS / 256, 256, 0, stream>>>(ws, out, 1);
    } else {
        // mode C: direct device atomics into d_out
        zero_out_kernel<<<(out_size + 255) / 256, 256, 0, stream>>>(out, out_size);
        morse_pairs_direct<<<NPAIRS / 1024, 256, 0, stream>>>(
            pos, cell, shifts, map, map + NPAIRS, out);
    }
}